// Round 4
// baseline (134.895 us; speedup 1.0000x reference)
//
#include <hip/hip_runtime.h>
#include <hip/hip_bf16.h>
#include <stdint.h>

#define B_    4
#define NN    4096
#define DIN   512
#define DOUT  256
#define ALPHA_ 0.2f

typedef __attribute__((ext_vector_type(8))) short short8;
typedef __attribute__((ext_vector_type(4))) float f32x4;

typedef const __attribute__((address_space(1))) void gconst_void;
typedef __attribute__((address_space(3))) void lds_void;

__device__ __forceinline__ unsigned short f2bf(float x) {
    union { float f; uint32_t u; } v; v.f = x;
    uint32_t r = v.u + 0x7FFFu + ((v.u >> 16) & 1u);
    return (unsigned short)(r >> 16);
}
__device__ __forceinline__ float bf2f(unsigned short u) {
    union { uint32_t u; float f; } v; v.u = ((uint32_t)u) << 16;
    return v.f;
}

// ---------------- K_prep: pack adj -> bits | h fp32->bf16 | Ws -> WsT bf16 ----------
__global__ __launch_bounds__(256) void k_prep(const int* __restrict__ adj,
                                              const float4* __restrict__ h4,
                                              const float* __restrict__ Ws,
                                              uint32_t* __restrict__ bits,
                                              uint2* __restrict__ hb,
                                              unsigned short* __restrict__ wst) {
    const int gid = blockIdx.x;
    const int tid = threadIdx.x;
    if (gid < 65536) {                       // pack adj: 67MB -> 2MB
        int idx = gid * 256 + tid;
        unsigned long long m = __ballot(adj[idx] > 0);
        if ((tid & 63) == 0)
            *reinterpret_cast<unsigned long long*>(bits + ((idx >> 6) << 1)) = m;
    } else if (gid < 73728) {                // h -> bf16 (float4 granularity)
        int idx = (gid - 65536) * 256 + tid;
        float4 v = h4[idx];
        uint2 o;
        o.x = (uint32_t)f2bf(v.x) | ((uint32_t)f2bf(v.y) << 16);
        o.y = (uint32_t)f2bf(v.z) | ((uint32_t)f2bf(v.w) << 16);
        hb[idx] = o;
    } else {                                 // Ws (B,DIN,DOUT) -> WsT (B,DOUT,DIN) bf16
        int idx = (gid - 73728) * 256 + tid;
        int k = idx & (DIN - 1);
        int o = (idx >> 9) & (DOUT - 1);
        int b = idx >> 17;
        wst[idx] = f2bf(Ws[((size_t)b * DIN + k) * DOUT + o]);
    }
}

// ---------------- K1: WhT[b][d][m] = (h @ Ws)^T + fused e1/e2 epilogue --------------
__global__ __launch_bounds__(256) void k_gemm1(const unsigned short* __restrict__ hb,
                                               const unsigned short* __restrict__ wst,
                                               const float* __restrict__ a,
                                               unsigned short* __restrict__ wht,
                                               float* __restrict__ e1,
                                               float* __restrict__ e2) {
    __shared__ unsigned short Ah[64 * 64];    // [n][k] swizzled rows (128B)
    __shared__ unsigned short Bw[256 * 64];   // [d][k] swizzled rows (128B)
    __shared__ float e1s[64], e2s[64];
    const int tid = threadIdx.x;
    const int w = tid >> 6, lane = tid & 63;
    const int l15 = lane & 15, lhi = lane >> 4;
    const int b = blockIdx.y;
    const int n0 = blockIdx.x * 64;
    const unsigned short* hrow = hb + ((size_t)b * NN + n0) * DIN;
    const unsigned short* wrow = wst + (size_t)b * DOUT * DIN;

    if (tid < 64) { e1s[tid] = 0.f; e2s[tid] = 0.f; }

    f32x4 acc[4][4] = {};

    for (int kt = 0; kt < DIN / 64; ++kt) {
        const int k0 = kt * 64;
        #pragma unroll
        for (int it = 0; it < 2; ++it) {     // stage A: 8KB
            int q = it * 256 + tid;
            int row = q >> 3, c = q & 7;
            const unsigned short* src = hrow + (size_t)row * DIN + k0 + 8 * (c ^ (row & 7));
            char* dst = reinterpret_cast<char*>(Ah) + it * 4096 + w * 1024;
            __builtin_amdgcn_global_load_lds((gconst_void*)src, (lds_void*)dst, 16, 0, 0);
        }
        #pragma unroll
        for (int it = 0; it < 8; ++it) {     // stage B: 32KB
            int q = it * 256 + tid;
            int row = q >> 3, c = q & 7;
            const unsigned short* src = wrow + (size_t)row * DIN + k0 + 8 * (c ^ (row & 7));
            char* dst = reinterpret_cast<char*>(Bw) + it * 4096 + w * 1024;
            __builtin_amdgcn_global_load_lds((gconst_void*)src, (lds_void*)dst, 16, 0, 0);
        }
        __syncthreads();
        #pragma unroll
        for (int kk = 0; kk < 2; ++kk) {
            short8 af[4], bfr[4];
            #pragma unroll
            for (int rf = 0; rf < 4; ++rf) {
                int row = rf * 16 + l15;
                int off = row * 128 + ((kk * 64 + lhi * 16) ^ ((row & 7) << 4));
                af[rf] = *reinterpret_cast<const short8*>(reinterpret_cast<const char*>(Ah) + off);
            }
            #pragma unroll
            for (int cf = 0; cf < 4; ++cf) {
                int row = w * 64 + cf * 16 + l15;
                int off = row * 128 + ((kk * 64 + lhi * 16) ^ ((row & 7) << 4));
                bfr[cf] = *reinterpret_cast<const short8*>(reinterpret_cast<const char*>(Bw) + off);
            }
            #pragma unroll
            for (int rf = 0; rf < 4; ++rf)
                #pragma unroll
                for (int cf = 0; cf < 4; ++cf)
                    acc[rf][cf] = __builtin_amdgcn_mfma_f32_16x16x32_bf16(af[rf], bfr[cf], acc[rf][cf], 0, 0, 0);
        }
        __syncthreads();
    }
    // WhT write (bf16, transposed)
    unsigned short* wb = wht + (size_t)b * DOUT * NN;
    #pragma unroll
    for (int rf = 0; rf < 4; ++rf) {
        #pragma unroll
        for (int cf = 0; cf < 4; ++cf) {
            int d = w * 64 + cf * 16 + l15;
            int m = n0 + rf * 16 + lhi * 4;
            uint2 pk;
            pk.x = (uint32_t)f2bf(acc[rf][cf][0]) | ((uint32_t)f2bf(acc[rf][cf][1]) << 16);
            pk.y = (uint32_t)f2bf(acc[rf][cf][2]) | ((uint32_t)f2bf(acc[rf][cf][3]) << 16);
            *reinterpret_cast<uint2*>(wb + (size_t)d * NN + m) = pk;
        }
    }
    // fused e1/e2: e1[m] = sum_d Wh[m][d]*a1[d] (fp32 acc, shfl-reduce over l15)
    const float* ab = a + b * 2 * DOUT;
    float a1v[4], a2v[4];
    #pragma unroll
    for (int cf = 0; cf < 4; ++cf) {
        int d = w * 64 + cf * 16 + l15;
        a1v[cf] = ab[d];
        a2v[cf] = ab[DOUT + d];
    }
    #pragma unroll
    for (int rf = 0; rf < 4; ++rf) {
        #pragma unroll
        for (int j = 0; j < 4; ++j) {
            float p1 = 0.f, p2 = 0.f;
            #pragma unroll
            for (int cf = 0; cf < 4; ++cf) {
                p1 = fmaf(acc[rf][cf][j], a1v[cf], p1);
                p2 = fmaf(acc[rf][cf][j], a2v[cf], p2);
            }
            #pragma unroll
            for (int msk = 1; msk < 16; msk <<= 1) {
                p1 += __shfl_xor(p1, msk);
                p2 += __shfl_xor(p2, msk);
            }
            if (l15 == 0) {
                atomicAdd(&e1s[rf * 16 + lhi * 4 + j], p1);
                atomicAdd(&e2s[rf * 16 + lhi * 4 + j], p2);
            }
        }
    }
    __syncthreads();
    if (tid < 64) {
        e1[b * NN + n0 + tid] = e1s[tid];
        e2[b * NN + n0 + tid] = e2s[tid];
    }
}

// ---------------- K4: h' = softmax(P)@Wh, unnormalized accumulate ------------------
// block: 32 n-rows x 128 d-cols, 4 waves (w = d-block) each 32n x 32d (acc 2x2)
// LDS exactly 40960B -> 4 blocks/CU, 16 waves/CU, 4 waves/SIMD
__global__ __launch_bounds__(256, 4) void k_attn(const unsigned short* __restrict__ wht,
                                                 const uint32_t* __restrict__ bits,
                                                 const float* __restrict__ e1,
                                                 const float* __restrict__ e2,
                                                 float* __restrict__ out) {
    __shared__ unsigned short Bw[2 * 128 * 64];  // WhT tile dbuf, swizzled 128B rows (32KB)
    __shared__ unsigned short Pt[2 * 32 * 64];   // P tile dbuf, swizzled 128B rows (8KB)
    // row-sum reciprocals overlay Pt after the K-loop (no extra LDS)
    float* sumsF = reinterpret_cast<float*>(Pt);

    const int tid = threadIdx.x;
    const int w = tid >> 6, lane = tid & 63;
    const int l15 = lane & 15, lhi = lane >> 4;

    // XCD-aware bijective swizzle: 1024 blocks % 8 == 0; each XCD -> one batch slice
    const int bid = blockIdx.x;
    const int wg = ((bid & 7) << 7) | (bid >> 3);
    const int b  = wg >> 8;
    const int r  = wg & 255;
    const int d0 = (r & 1) << 7;      // 0 or 128
    const int n0 = (r >> 1) << 5;     // 32-row chunk

    // P-compute mapping: pr = row (0..31), pc = 8-col group (0..7)
    const int pr = tid >> 3, pc = tid & 7;
    const int gn = n0 + pr;
    const float r1 = e1[b * NN + gn];
    const float r2 = ALPHA_ * r1;
    const uint8_t* browb = reinterpret_cast<const uint8_t*>(bits) + (size_t)gn * (NN / 8);
    const float* e2g = e2 + b * NN;
    const unsigned short* wb = wht + (size_t)b * DOUT * NN;

    f32x4 acc[2][2] = {};
    float psum = 0.f;

    // ---- prologue: stage tile 0, compute P(0) ----
    #pragma unroll
    for (int it = 0; it < 4; ++it) {
        int q = it * 256 + tid;
        int row = q >> 3, c = q & 7;
        const unsigned short* src = wb + (size_t)(d0 + row) * NN + 8 * (c ^ (row & 7));
        char* dst = reinterpret_cast<char*>(Bw) + it * 4096 + w * 1024;
        __builtin_amdgcn_global_load_lds((gconst_void*)src, (lds_void*)dst, 16, 0, 0);
    }
    {
        uint32_t bb = browb[pc];
        const float4* ep = reinterpret_cast<const float4*>(e2g + pc * 8);
        float4 ea = ep[0], eb = ep[1];
        float pv[8] = {ea.x, ea.y, ea.z, ea.w, eb.x, eb.y, eb.z, eb.w};
        #pragma unroll
        for (int j = 0; j < 8; ++j) {
            float s = r1 + pv[j];
            float t = fmaf(ALPHA_, pv[j], r2);
            float p = __expf(fmaxf(s, t));
            uint32_t msk = (uint32_t)(((int32_t)(bb << (31 - j))) >> 31);
            union { float f; uint32_t u; } pu; pu.f = p; pu.u &= msk;
            pv[j] = pu.f;
            psum += pv[j];
        }
        union { short8 v; uint32_t u[4]; } k0;
        #pragma unroll
        for (int i = 0; i < 4; ++i) {
            union { __hip_bfloat162 h; uint32_t u; } c0;
            c0.h = __float22bfloat162_rn(float2{pv[2 * i], pv[2 * i + 1]});
            k0.u[i] = c0.u;
        }
        *reinterpret_cast<short8*>(reinterpret_cast<char*>(Pt) + pr * 128 +
                                   ((pc * 16) ^ ((pr & 7) << 4))) = k0.v;
    }
    __syncthreads();

    // ---- main loop: 1 barrier/tile, stage(t+1) + P(t+1) overlapped with MFMA(t) ----
    #pragma unroll 2
    for (int t = 0; t < NN / 64; ++t) {
        const int cur = t & 1;
        uint32_t bbN = 0;
        float4 ea, eb;
        if (t < NN / 64 - 1) {
            const int m1 = (t + 1) * 64;
            #pragma unroll
            for (int it = 0; it < 4; ++it) {
                int q = it * 256 + tid;
                int row = q >> 3, c = q & 7;
                const unsigned short* src = wb + (size_t)(d0 + row) * NN + m1 + 8 * (c ^ (row & 7));
                char* dst = reinterpret_cast<char*>(Bw) + (cur ^ 1) * 16384 + it * 4096 + w * 1024;
                __builtin_amdgcn_global_load_lds((gconst_void*)src, (lds_void*)dst, 16, 0, 0);
            }
            bbN = browb[(m1 >> 3) + pc];
            const float4* ep = reinterpret_cast<const float4*>(e2g + m1 + pc * 8);
            ea = ep[0]; eb = ep[1];
        }
        // MFMA phase on buffers [cur]
        __builtin_amdgcn_s_setprio(1);
        #pragma unroll
        for (int kk = 0; kk < 2; ++kk) {
            short8 af[2], bfr[2];
            #pragma unroll
            for (int rf = 0; rf < 2; ++rf) {
                int row = rf * 16 + l15;
                int off = row * 128 + ((kk * 64 + lhi * 16) ^ ((row & 7) << 4));
                af[rf] = *reinterpret_cast<const short8*>(
                    reinterpret_cast<const char*>(Pt) + cur * 4096 + off);
            }
            #pragma unroll
            for (int cf = 0; cf < 2; ++cf) {
                int row = w * 32 + cf * 16 + l15;
                int off = row * 128 + ((kk * 64 + lhi * 16) ^ ((row & 7) << 4));
                bfr[cf] = *reinterpret_cast<const short8*>(
                    reinterpret_cast<const char*>(Bw) + cur * 16384 + off);
            }
            #pragma unroll
            for (int rf = 0; rf < 2; ++rf)
                #pragma unroll
                for (int cf = 0; cf < 2; ++cf)
                    acc[rf][cf] = __builtin_amdgcn_mfma_f32_16x16x32_bf16(af[rf], bfr[cf], acc[rf][cf], 0, 0, 0);
        }
        __builtin_amdgcn_s_setprio(0);
        if (t < NN / 64 - 1) {
            float pv[8] = {ea.x, ea.y, ea.z, ea.w, eb.x, eb.y, eb.z, eb.w};
            #pragma unroll
            for (int j = 0; j < 8; ++j) {
                float s = r1 + pv[j];
                float tt = fmaf(ALPHA_, pv[j], r2);
                float p = __expf(fmaxf(s, tt));
                uint32_t msk = (uint32_t)(((int32_t)(bbN << (31 - j))) >> 31);
                union { float f; uint32_t u; } pu; pu.f = p; pu.u &= msk;
                pv[j] = pu.f;
                psum += pv[j];
            }
            union { short8 v; uint32_t u[4]; } k0;
            #pragma unroll
            for (int i = 0; i < 4; ++i) {
                union { __hip_bfloat162 h; uint32_t u; } c0;
                c0.h = __float22bfloat162_rn(float2{pv[2 * i], pv[2 * i + 1]});
                k0.u[i] = c0.u;
            }
            *reinterpret_cast<short8*>(reinterpret_cast<char*>(Pt) + (cur ^ 1) * 4096 + pr * 128 +
                                       ((pc * 16) ^ ((pr & 7) << 4))) = k0.v;
            __syncthreads();
        }
    }
    // ---- epilogue: row-sum reduce -> reciprocal in LDS (Pt overlay), ELU, store ----
    psum += __shfl_xor(psum, 1);
    psum += __shfl_xor(psum, 2);
    psum += __shfl_xor(psum, 4);
    __syncthreads();                   // all MFMA reads of Pt done before overlay
    if ((tid & 7) == 0) sumsF[pr] = 1.0f / psum;
    __syncthreads();
    #pragma unroll
    for (int rf = 0; rf < 2; ++rf) {
        #pragma unroll
        for (int cf = 0; cf < 2; ++cf) {
            int d = d0 + w * 32 + cf * 16 + l15;
            #pragma unroll
            for (int j = 0; j < 4; ++j) {
                int lr = rf * 16 + lhi * 4 + j;
                float x = acc[rf][cf][j] * sumsF[lr];
                x = x > 0.f ? x : (__expf(x) - 1.f);
                out[((size_t)b * NN + n0 + lr) * DOUT + d] = x;
            }
        }
    }
}

extern "C" void kernel_launch(void* const* d_in, const int* in_sizes, int n_in,
                              void* d_out, int out_size, void* d_ws, size_t ws_size,
                              hipStream_t stream) {
    (void)in_sizes; (void)n_in; (void)out_size; (void)ws_size;
    const float* h   = (const float*)d_in[0];
    const int*   adj = (const int*)d_in[1];
    const float* Ws  = (const float*)d_in[2];
    const float* a   = (const float*)d_in[3];
    float* out = (float*)d_out;

    char* ws = (char*)d_ws;
    unsigned short* hb  = (unsigned short*)(ws);              // 16,777,216 B
    unsigned short* wst = (unsigned short*)(ws + 16777216);   //  1,048,576 B
    unsigned short* wht = (unsigned short*)(ws + 17825792);   //  8,388,608 B
    float* e1  = (float*)(ws + 26214400);                     //     65,536 B
    float* e2  = (float*)(ws + 26279936);                     //     65,536 B
    uint32_t* bits = (uint32_t*)(ws + 26476544);              //  2,097,152 B

    k_prep<<<dim3(75776), dim3(256), 0, stream>>>(adj, (const float4*)h, Ws,
                                                  bits, (uint2*)hb, wst);
    k_gemm1<<<dim3(NN / 64, B_), dim3(256), 0, stream>>>(hb, wst, a, wht, e1, e2);
    k_attn<<<dim3(1024), dim3(256), 0, stream>>>(wht, bits, e1, e2, out);
}